// Round 10
// baseline (776.962 us; speedup 1.0000x reference)
//
#include <hip/hip_runtime.h>
#include <math.h>

// Sinkhorn loss, B=8, S=2048, P=1024, D=2, eps=0.01, 50 iters.
// PERSISTENT-KERNEL v10 — dual-batch interleaved schedule.
// R9 evidence: VALU-busy ~295us but wall 567us; stall ~270us = 100 serial
// barrier settles (store->L3 ~1us + poll RTT + staging RTT) that nothing
// in-batch can hide (f->g strictly serial). Fix: each block serves TWO
// batches (group of 64 blocks <-> batch pair), rotation fA,fB,gA,gB with
// split arrive/wait version counters — every wait is preceded by a full
// phase of the other batch, hiding the settle under compute.
// WAR-safety: gA(t) overwrites G2_A only after wait(fdA,t+1) == all peers
// done with their fA staging reads of G2_A (and symmetrically for F2).
// Components proven: R7 store/poll barrier, R9 pk+SoA inner loops, R8
// partial-LSE LDS merge (g: 4 cols/wave x quarter-tile; x-coords from
// L1-hot global float4 to fit two batches in ~41KB LDS).
// Base-2 scaled potentials: F2 = f/(eps*ln2), G2 = g/(eps*ln2), K = 100*log2(e)
//   f elem: u = 2K*x.y + (G2[p] - K*y2[p]);  F2 = (K*x2 - log2 S) - LSE2(u)
//   g elem: u = 2K*x.y + (F2[s] - K*x2[s]);  G2 = (K*y2 + logb2) - LSE2(u)

#define BB 8
#define SS 2048
#define PP 1024
#define NEG_INF -1e9f
#define LOG2S 11.0f
#define ITERS 50
#define K2E 144.269504088896f   /* 100*log2(e) */
#define TWOK 288.539008177792f  /* 200*log2(e) */
#define NBLK 256
#define NTHR 1024

typedef float v2f __attribute__((ext_vector_type(2)));

__device__ __forceinline__ float fexp2(float x) {
  return __builtin_amdgcn_exp2f(x);
}
__device__ __forceinline__ float flog2(float x) {
  return __builtin_amdgcn_logf(x);
}
__device__ __forceinline__ v2f vfma(v2f a, v2f b, v2f c) {
  return __builtin_elementwise_fma(a, b, c);
}
__device__ __forceinline__ v2f vmax(v2f a, v2f b) {
  return __builtin_elementwise_max(a, b);
}

// agent-scope coherent (cache-bypassing) accessors, RELAXED only (proven R6+)
__device__ __forceinline__ float coh_load(const float* p) {
  return __hip_atomic_load((float*)p, __ATOMIC_RELAXED, __HIP_MEMORY_SCOPE_AGENT);
}
__device__ __forceinline__ void coh_store(float* p, float v) {
  __hip_atomic_store(p, v, __ATOMIC_RELAXED, __HIP_MEMORY_SCOPE_AGENT);
}
__device__ __forceinline__ int coh_loadi(const int* p) {
  return __hip_atomic_load((int*)p, __ATOMIC_RELAXED, __HIP_MEMORY_SCOPE_AGENT);
}
__device__ __forceinline__ void coh_storei(int* p, int v) {
  __hip_atomic_store(p, v, __ATOMIC_RELAXED, __HIP_MEMORY_SCOPE_AGENT);
}

// split barrier: arrive (syncthreads drains all waves' stores, then t0 posts
// version), wait (wave0 polls 64 slots one-per-lane until __all >= ver).
__device__ __forceinline__ void arrive(int* slot, int ver) {
  __syncthreads();
  asm volatile("" ::: "memory");
  if (threadIdx.x == 0) coh_storei(slot, ver);
}
__device__ __forceinline__ void wait_all(int* slots, int ver, int w, int lane) {
  if (w == 0) {
    for (;;) {
      int v = coh_loadi(&slots[lane]);
      if (__all(v >= ver)) break;
      __builtin_amdgcn_s_sleep(1);
    }
  }
  asm volatile("" ::: "memory");
  __syncthreads();
}

// ws layout (bytes):
//   G2    : [0,      32768)   B*P float
//   F2    : [32768,  98304)   B*S float
//   logb2 : [98304, 131072)   B*P float
//   fdone : [131072, 133120)  8 batches x 64 ints (version slots)
//   gdone : [133120, 135168)  8 batches x 64 ints

__global__ __launch_bounds__(1024) void setup_kernel(
    const int* __restrict__ labels, float* __restrict__ G2,
    float* __restrict__ logb2, int* __restrict__ fdone,
    int* __restrict__ gdone, float* __restrict__ out) {
  __shared__ int c[PP];
  int b = blockIdx.x;
  int t = threadIdx.x;  // 1024 threads
  c[t] = 0;
  __syncthreads();
  atomicAdd(&c[labels[b * SS + t] & (PP - 1)], 1);
  atomicAdd(&c[labels[b * SS + PP + t] & (PP - 1)], 1);
  __syncthreads();
  int cc = c[t];
  logb2[b * PP + t] = (cc > 0) ? (flog2((float)cc) - LOG2S) : NEG_INF;
  G2[b * PP + t] = 0.0f;
  if (t < 64) {
    fdone[(b << 6) + t] = 0;
    gdone[(b << 6) + t] = 0;
  }
  if (t == 0 && b == 0) out[0] = 0.0f;
}

// f-phase for one batch: 2 rows/wave, full 1024-col tile from LDS SoA,
// pk online LSE (R9 structure, r<2). F2out = F2g + frow (2 rows).
__device__ __forceinline__ void f_phase(const float* fy0, const float* fy1,
                                        const float* fq,
                                        const float2* preds2, int frow,
                                        float* F2out, int lane) {
  float2 fx0 = preds2[frow];
  float2 fx1 = preds2[frow + 1];
  float fk0[2] = {TWOK * fx0.x, TWOK * fx1.x};
  float fk1[2] = {TWOK * fx0.y, TWOK * fx1.y};
  float fc0[2] = {fmaf(K2E, fx0.x * fx0.x + fx0.y * fx0.y, -LOG2S),
                  fmaf(K2E, fx1.x * fx1.x + fx1.y * fx1.y, -LOG2S)};
  float m[2];
  v2f s[2];
#pragma unroll
  for (int r = 0; r < 2; ++r) { m[r] = -3.4e38f; s[r] = (v2f)(0.0f); }
#pragma unroll
  for (int ch = 0; ch < 2; ++ch) {
    v2f a0[4], a1[4], aq[4];
#pragma unroll
    for (int i = 0; i < 4; ++i) {
      int pi = (ch << 8) + (i << 6) + lane;  // pair index, consecutive lanes
      a0[i] = *(const v2f*)&fy0[pi << 1];
      a1[i] = *(const v2f*)&fy1[pi << 1];
      aq[i] = *(const v2f*)&fq[pi << 1];
    }
#pragma unroll
    for (int r = 0; r < 2; ++r) {
      v2f K0 = (v2f)(fk0[r]), K1 = (v2f)(fk1[r]);
      v2f u0 = vfma(K0, a0[0], vfma(K1, a1[0], aq[0]));
      v2f u1 = vfma(K0, a0[1], vfma(K1, a1[1], aq[1]));
      v2f u2 = vfma(K0, a0[2], vfma(K1, a1[2], aq[2]));
      v2f u3 = vfma(K0, a0[3], vfma(K1, a1[3], aq[3]));
      v2f cm2 = vmax(vmax(u0, u1), vmax(u2, u3));
      float mn = fmaxf(m[r], fmaxf(cm2.x, cm2.y));
      float sc = fexp2(m[r] - mn);
      v2f mn2 = (v2f)(mn);
      v2f d0 = u0 - mn2, d1 = u1 - mn2, d2 = u2 - mn2, d3 = u3 - mn2;
      v2f e0 = {fexp2(d0.x), fexp2(d0.y)};
      v2f e1 = {fexp2(d1.x), fexp2(d1.y)};
      v2f e2 = {fexp2(d2.x), fexp2(d2.y)};
      v2f e3 = {fexp2(d3.x), fexp2(d3.y)};
      s[r] = vfma(s[r], (v2f)(sc), (e0 + e1) + (e2 + e3));
      m[r] = mn;
    }
  }
  float fout = 0.0f;
#pragma unroll
  for (int r = 0; r < 2; ++r) {
    float M = m[r];
#pragma unroll
    for (int off = 1; off <= 32; off <<= 1)
      M = fmaxf(M, __shfl_xor(M, off, 64));
    float sr = (s[r].x + s[r].y) * fexp2(m[r] - M);
#pragma unroll
    for (int off = 1; off <= 32; off <<= 1) sr += __shfl_xor(sr, off, 64);
    float v = fc0[r] - M - flog2(sr);
    if (lane == r) fout = v;
  }
  if (lane < 2) coh_store(&F2out[lane], fout);
}

// g-phase for one batch: 4 cols/wave x quarter tile (x-coords from L1-hot
// global float4, q from LDS), pk LSE + R8-style LDS partial merge.
// G2out = G2g + gcol (4 cols, stored by merge waves).
__device__ __forceinline__ void g_phase(const float4* x4, const float* gq,
                                        const float2* pos2,
                                        const float* __restrict__ logb2,
                                        int gcol, int w, int tq, int lane,
                                        float2 (*part)[4], float* G2out) {
  float gk0[4], gk1[4], gc0[4];
#pragma unroll
  for (int c = 0; c < 4; ++c) {
    float2 gy = pos2[gcol + c];  // wave-uniform broadcast
    gk0[c] = TWOK * gy.x;
    gk1[c] = TWOK * gy.y;
    gc0[c] = fmaf(K2E, gy.x * gy.x + gy.y * gy.y, logb2[gcol + c]);
  }
  // one quarter = 4 pair-loads per lane
  v2f a0[4], a1[4], aq[4];
#pragma unroll
  for (int i = 0; i < 4; ++i) {
    int pi = (tq << 8) + (i << 6) + lane;
    float4 v = x4[pi];               // (x0,x1,x0',x1') — L1-hot
    a0[i] = (v2f){v.x, v.z};
    a1[i] = (v2f){v.y, v.w};
    aq[i] = *(const v2f*)&gq[pi << 1];
  }
  float2 myp = make_float2(0.0f, 0.0f);
#pragma unroll
  for (int c = 0; c < 4; ++c) {
    v2f K0 = (v2f)(gk0[c]), K1 = (v2f)(gk1[c]);
    v2f u0 = vfma(K0, a0[0], vfma(K1, a1[0], aq[0]));
    v2f u1 = vfma(K0, a0[1], vfma(K1, a1[1], aq[1]));
    v2f u2 = vfma(K0, a0[2], vfma(K1, a1[2], aq[2]));
    v2f u3 = vfma(K0, a0[3], vfma(K1, a1[3], aq[3]));
    v2f cm2 = vmax(vmax(u0, u1), vmax(u2, u3));
    float M = fmaxf(cm2.x, cm2.y);
#pragma unroll
    for (int off = 1; off <= 32; off <<= 1)
      M = fmaxf(M, __shfl_xor(M, off, 64));
    v2f M2 = (v2f)(M);
    v2f d0 = u0 - M2, d1 = u1 - M2, d2 = u2 - M2, d3 = u3 - M2;
    v2f es = ((v2f){fexp2(d0.x), fexp2(d0.y)} +
              (v2f){fexp2(d1.x), fexp2(d1.y)}) +
             ((v2f){fexp2(d2.x), fexp2(d2.y)} +
              (v2f){fexp2(d3.x), fexp2(d3.y)});
    float S = es.x + es.y;
#pragma unroll
    for (int off = 1; off <= 32; off <<= 1) S += __shfl_xor(S, off, 64);
    if (lane == c) myp = make_float2(M - gc0[c], S);
  }
  if (lane < 4) part[w][lane] = myp;
  __syncthreads();
  if (tq == 0 && lane < 4) {  // merge the 4 quarters (waves w..w+3 share cg)
    float2 p0 = part[w][lane], p1 = part[w + 1][lane];
    float2 p2 = part[w + 2][lane], p3 = part[w + 3][lane];
    float M = fmaxf(fmaxf(p0.x, p1.x), fmaxf(p2.x, p3.x));
    float S = p0.y * fexp2(p0.x - M) + p1.y * fexp2(p1.x - M) +
              p2.y * fexp2(p2.x - M) + p3.y * fexp2(p3.x - M);
    coh_store(&G2out[lane], -M - flog2(S));
  }
  // no trailing sync needed: the arrive() that follows begins with one.
}

__global__ __launch_bounds__(1024) void sinkhorn_persist(
    const float* __restrict__ preds, const float* __restrict__ pos,
    const float* __restrict__ logb2, float* __restrict__ F2g,
    float* __restrict__ G2g, int* __restrict__ fdone,
    int* __restrict__ gdone, float* __restrict__ out) {
  __shared__ __align__(16) float fy0A[PP], fy1A[PP], fqA[PP];  // 12 KB
  __shared__ __align__(16) float fy0B[PP], fy1B[PP], fqB[PP];  // 12 KB
  __shared__ __align__(16) float gqA[SS], gqB[SS];             // 16 KB
  __shared__ float2 part[16][4];
  __shared__ float spart;
  const int t = threadIdx.x;    // 1024 threads, 16 waves
  const int blk = blockIdx.x;   // 256 blocks = 1/CU (proven geometry)
  const int grp = blk >> 6;     // 4 groups x 64 blocks
  const int sub = blk & 63;
  const int bbA = grp << 1, bbB = (grp << 1) + 1;
  int* fdA = fdone + (bbA << 6);
  int* fdB = fdone + (bbB << 6);
  int* gdA = gdone + (bbA << 6);
  int* gdB = gdone + (bbB << 6);
  const float2* pos2 = (const float2*)pos;
  const float2* preds2 = (const float2*)preds;
  const float4* xA4 = (const float4*)(preds + ((size_t)bbA << 12));
  const float4* xB4 = (const float4*)(preds + ((size_t)bbB << 12));
  float* G2A = G2g + (bbA << 10);
  float* G2B = G2g + (bbB << 10);
  float* F2A = F2g + (bbA << 11);
  float* F2B = F2g + (bbB << 11);

  // ---- persistent init: y coords into LDS SoA + K-scale norms in regs
  float yr2A, yr2B, xr2A[2], xr2B[2];
  {
    float2 y = pos2[(bbA << 10) + t];
    yr2A = y.x * y.x + y.y * y.y;
    fy0A[t] = y.x;
    fy1A[t] = y.y;
  }
  {
    float2 y = pos2[(bbB << 10) + t];
    yr2B = y.x * y.x + y.y * y.y;
    fy0B[t] = y.x;
    fy1B[t] = y.y;
  }
#pragma unroll
  for (int k = 0; k < 2; ++k) {
    int e = t + (k << 10);
    float2 xa = preds2[(bbA << 11) + e];
    xr2A[k] = xa.x * xa.x + xa.y * xa.y;
    float2 xb = preds2[(bbB << 11) + e];
    xr2B[k] = xb.x * xb.x + xb.y * xb.y;
  }

  const int w = t >> 6, lane = t & 63;
  const int frowA = (bbA << 11) + (sub << 5) + (w << 1);  // 2 f-rows/wave
  const int frowB = (bbB << 11) + (sub << 5) + (w << 1);
  const int cg = w >> 2, tq = w & 3;
  const int gcolA = (bbA << 10) + (sub << 4) + (cg << 2);  // 4 g-cols/wave
  const int gcolB = (bbB << 10) + (sub << 4) + (cg << 2);

  for (int it = 0; it < ITERS; ++it) {
    // ===== fA: needs gA(it-1); wait settled during previous gB =====
    wait_all(gdA, it, w, lane);
    fqA[t] = fmaf(-K2E, yr2A, coh_load(&G2A[t]));
    __syncthreads();
    f_phase(fy0A, fy1A, fqA, preds2, frowA, F2g + frowA, lane);
    arrive(&fdA[sub], it + 1);

    // ===== fB: wait settled during fA =====
    wait_all(gdB, it, w, lane);
    fqB[t] = fmaf(-K2E, yr2B, coh_load(&G2B[t]));
    __syncthreads();
    f_phase(fy0B, fy1B, fqB, preds2, frowB, F2g + frowB, lane);
    arrive(&fdB[sub], it + 1);

    // ===== gA: needs fA(it); wait settled during fB =====
    wait_all(fdA, it + 1, w, lane);
#pragma unroll
    for (int k = 0; k < 2; ++k) {
      int e = t + (k << 10);
      gqA[e] = fmaf(-K2E, xr2A[k], coh_load(&F2A[e]));
    }
    __syncthreads();
    g_phase(xA4, gqA, pos2, logb2, gcolA, w, tq, lane, part, G2g + gcolA);
    arrive(&gdA[sub], it + 1);

    // ===== gB: wait settled during gA =====
    wait_all(fdB, it + 1, w, lane);
#pragma unroll
    for (int k = 0; k < 2; ++k) {
      int e = t + (k << 10);
      gqB[e] = fmaf(-K2E, xr2B[k], coh_load(&F2B[e]));
    }
    __syncthreads();
    g_phase(xB4, gqB, pos2, logb2, gcolB, w, tq, lane, part, G2g + gcolB);
    arrive(&gdB[sub], it + 1);
  }

  // ---- fused final: restage qy with final G2, rowsum over 32+32 rows
  wait_all(gdA, ITERS, w, lane);
  wait_all(gdB, ITERS, w, lane);
  if (t == 0) spart = 0.0f;
  fqA[t] = fmaf(-K2E, yr2A, coh_load(&G2A[t]));
  fqB[t] = fmaf(-K2E, yr2B, coh_load(&G2B[t]));
  __syncthreads();
  float acc = 0.0f;
#pragma unroll
  for (int rr = 0; rr < 2; ++rr) {
    int row = frowA + rr;
    float2 x = preds2[row];
    float x2 = x.x * x.x + x.y * x.y;
    float qx = fmaf(-K2E, x2, coh_load(&F2g[row]));
#pragma unroll
    for (int i = 0; i < 16; ++i) {
      int p = (i << 6) + lane;
      float ay0 = fy0A[p], ay1 = fy1A[p], aqz = fqA[p];
      float y2 = fmaf(ay0, ay0, ay1 * ay1);
      float tt = fmaf(x.y, ay1, x.x * ay0);
      float c = fmaxf(x2 + y2 - 2.0f * tt, 0.0f);  // clamped cost
      float v2 = fmaf(TWOK, tt, aqz + qx);         // -K*C' + F2 + G2 (base-2)
      acc = fmaf(fexp2(v2), c, acc);               // c==0 kills C'<0 case
    }
  }
#pragma unroll
  for (int rr = 0; rr < 2; ++rr) {
    int row = frowB + rr;
    float2 x = preds2[row];
    float x2 = x.x * x.x + x.y * x.y;
    float qx = fmaf(-K2E, x2, coh_load(&F2g[row]));
#pragma unroll
    for (int i = 0; i < 16; ++i) {
      int p = (i << 6) + lane;
      float ay0 = fy0B[p], ay1 = fy1B[p], aqz = fqB[p];
      float y2 = fmaf(ay0, ay0, ay1 * ay1);
      float tt = fmaf(x.y, ay1, x.x * ay0);
      float c = fmaxf(x2 + y2 - 2.0f * tt, 0.0f);
      float v2 = fmaf(TWOK, tt, aqz + qx);
      acc = fmaf(fexp2(v2), c, acc);
    }
  }
#pragma unroll
  for (int off = 32; off; off >>= 1) acc += __shfl_xor(acc, off, 64);
  if (lane == 0) atomicAdd(&spart, acc);
  __syncthreads();
  if (t == 0) atomicAdd(out, spart * (1.0f / (float)BB));
}

extern "C" void kernel_launch(void* const* d_in, const int* in_sizes, int n_in,
                              void* d_out, int out_size, void* d_ws,
                              size_t ws_size, hipStream_t stream) {
  const float* preds = (const float*)d_in[0];  // [B,S,2]
  const int* labels = (const int*)d_in[1];     // [B,S]
  const float* pos = (const float*)d_in[2];    // [B,P,2]
  float* out = (float*)d_out;
  char* ws = (char*)d_ws;
  float* G2 = (float*)(ws);
  float* F2 = (float*)(ws + 32768);
  float* logb2 = (float*)(ws + 98304);
  int* fdone = (int*)(ws + 131072);
  int* gdone = (int*)(ws + 133120);

  hipLaunchKernelGGL(setup_kernel, dim3(BB), dim3(1024), 0, stream, labels, G2,
                     logb2, fdone, gdone, out);
  hipLaunchKernelGGL(sinkhorn_persist, dim3(NBLK), dim3(NTHR), 0, stream,
                     preds, pos, logb2, F2, G2, fdone, gdone, out);
}

// Round 11
// 612.015 us; speedup vs baseline: 1.2695x; 1.2695x over previous
//
#include <hip/hip_runtime.h>
#include <math.h>

// Sinkhorn loss, B=8, S=2048, P=1024, D=2, eps=0.01, 50 iters.
// PERSISTENT-KERNEL v11 — R9 compute + version-stamped dataflow sync
// (no barriers at all).
// R10 post-mortem: dual-batch interleave REGRESSED (777us): +VALU (extra
// butterflies), 2x sync points, half-size phases, 4x uncached staging.
// Reverted to R9 (567us). R9's stall (~270us) = 2 serialized L3 RTTs per
// phase: barrier-slot poll THEN staging reads, gated on slowest block's
// full compute. v11 packs each potential as 8B (value, iter-stamp) stored
// with one relaxed agent-scope 64b store; consumers poll the stamped entry
// in the staging loop itself — staging read IS the wait (1 RTT), and
// resumes on the producing LANES' stores, not a block-wide barrier.
// WAR-safe single-buffered: overwriting F2 stamp it+2 requires f(it+1)
// complete -> all G2 stamp it+1 -> every block finished reading F2 stamp
// it+1 (a still-spinning reader blocks the whole overwrite chain); symm.
// for G2. Stamps: setup writes G2 stamp 0; f(it) reads G2 stamp it, writes
// F2 stamp it+1; g(it) reads F2 stamp it+1, writes G2 stamp it+1.
// Base-2 scaled potentials: F2 = f/(eps*ln2), G2 = g/(eps*ln2), K = 100*log2(e)
//   f elem: u = 2K*x.y + (G2[p] - K*y2[p]);  F2 = (K*x2 - log2 S) - LSE2(u)
//   g elem: u = 2K*x.y + (F2[s] - K*x2[s]);  G2 = (K*y2 + logb2) - LSE2(u)

#define BB 8
#define SS 2048
#define PP 1024
#define NEG_INF -1e9f
#define LOG2S 11.0f
#define ITERS 50
#define K2E 144.269504088896f   /* 100*log2(e) */
#define TWOK 288.539008177792f  /* 200*log2(e) */
#define NBLK 256
#define NTHR 1024

typedef float v2f __attribute__((ext_vector_type(2)));
typedef unsigned long long u64;

__device__ __forceinline__ float fexp2(float x) {
  return __builtin_amdgcn_exp2f(x);
}
__device__ __forceinline__ float flog2(float x) {
  return __builtin_amdgcn_logf(x);
}
__device__ __forceinline__ v2f vfma(v2f a, v2f b, v2f c) {
  return __builtin_elementwise_fma(a, b, c);
}
__device__ __forceinline__ v2f vmax(v2f a, v2f b) {
  return __builtin_elementwise_max(a, b);
}

// agent-scope coherent (cache-bypassing) 64-bit accessors, RELAXED (R6+)
__device__ __forceinline__ u64 coh_load64(const u64* p) {
  return __hip_atomic_load((u64*)p, __ATOMIC_RELAXED, __HIP_MEMORY_SCOPE_AGENT);
}
__device__ __forceinline__ void coh_store64(u64* p, u64 v) {
  __hip_atomic_store(p, v, __ATOMIC_RELAXED, __HIP_MEMORY_SCOPE_AGENT);
}
__device__ __forceinline__ u64 pack_vs(float val, unsigned stamp) {
  return ((u64)stamp << 32) | (u64)__float_as_uint(val);
}
// poll a stamped entry until its version matches; returns the value
__device__ __forceinline__ float wait_val(const u64* p, unsigned stamp) {
  u64 v = coh_load64(p);
  while ((unsigned)(v >> 32) != stamp) {
    __builtin_amdgcn_s_sleep(1);
    v = coh_load64(p);
  }
  return __uint_as_float((unsigned)v);
}

// ws layout (bytes):
//   G2v   : [0,      65536)   B*P u64 (value, stamp)
//   F2v   : [65536,  196608)  B*S u64 (value, stamp)
//   logb2 : [196608, 229376)  B*P float

__global__ __launch_bounds__(1024) void setup_kernel(
    const int* __restrict__ labels, u64* __restrict__ G2v,
    float* __restrict__ logb2, float* __restrict__ out) {
  __shared__ int c[PP];
  int b = blockIdx.x;
  int t = threadIdx.x;  // 1024 threads
  c[t] = 0;
  __syncthreads();
  atomicAdd(&c[labels[b * SS + t] & (PP - 1)], 1);
  atomicAdd(&c[labels[b * SS + PP + t] & (PP - 1)], 1);
  __syncthreads();
  int cc = c[t];
  logb2[b * PP + t] = (cc > 0) ? (flog2((float)cc) - LOG2S) : NEG_INF;
  G2v[b * PP + t] = pack_vs(0.0f, 0u);  // initial G2 = 0, stamp 0
  if (t == 0 && b == 0) out[0] = 0.0f;
}

__global__ __launch_bounds__(1024) void sinkhorn_persist(
    const float* __restrict__ preds, const float* __restrict__ pos,
    const float* __restrict__ logb2, u64* __restrict__ F2v,
    u64* __restrict__ G2v, float* __restrict__ out) {
  // SoA LDS tiles: element-pair reads are pk-ready reg pairs (R9)
  __shared__ __align__(16) float fy0[PP], fy1[PP], fq[PP];        // 12 KB
  __shared__ __align__(16) float gx0[SS], gx1[SS], gq[SS];        // 24 KB
  __shared__ float spart;
  const int t = threadIdx.x;    // 1024 threads, 16 waves
  const int blk = blockIdx.x;   // 256 blocks = 1/CU (proven geometry)
  const int bb = blk >> 5;      // 32 blocks per batch
  u64* G2b = G2v + (bb << 10);
  u64* F2b = F2v + (bb << 11);
  const float2* pos2 = (const float2*)pos;
  const float2* preds2 = (const float2*)preds;

  // ---- persistent init: x/y constants into LDS + K-scaled norms in regs
  float yr2, xr2[2];
  {
    float2 y = pos2[(bb << 10) + t];
    yr2 = y.x * y.x + y.y * y.y;
    fy0[t] = y.x;
    fy1[t] = y.y;
  }
#pragma unroll
  for (int k = 0; k < 2; ++k) {
    int e = t + (k << 10);
    float2 x = preds2[(bb << 11) + e];
    xr2[k] = x.x * x.x + x.y * x.y;
    gx0[e] = x.x;
    gx1[e] = x.y;
  }

  const int w = t >> 6, lane = t & 63;
  // f-phase: wave w owns 4 rows [blk*64 + w*4, +4); lane scans 8 elem-pairs
  const int frowb = (blk << 6) + (w << 2);
  float fk0[4], fk1[4], fc0[4];
#pragma unroll
  for (int r = 0; r < 4; ++r) {
    float2 fx = preds2[frowb + r];  // wave-uniform broadcast load
    fk0[r] = TWOK * fx.x;
    fk1[r] = TWOK * fx.y;
    fc0[r] = fmaf(K2E, fx.x * fx.x + fx.y * fx.y, -LOG2S);
  }
  // g-phase: wave w owns 2 cols [blk*32 + w*2, +2); lane scans 16 elem-pairs
  const int gcolb = (blk << 5) + (w << 1);
  float gk0[2], gk1[2], gc0[2];
#pragma unroll
  for (int c = 0; c < 2; ++c) {
    float2 gy = pos2[gcolb + c];
    gk0[c] = TWOK * gy.x;
    gk1[c] = TWOK * gy.y;
    gc0[c] = fmaf(K2E, gy.x * gy.x + gy.y * gy.y, logb2[gcolb + c]);
  }

  for (int it = 0; it < ITERS; ++it) {
    const unsigned sF = (unsigned)(it + 1);  // stamp f writes / g expects
    const unsigned sG = (unsigned)it;        // stamp f expects (g wrote it)
    // ---- stage qy = G2 - K*y2 : poll-stamped read IS the wait
    fq[t] = fmaf(-K2E, yr2, wait_val(&G2b[t], sG));
    __syncthreads();
    // ---- f-compute: online LSE over pairs, 4 rows/lane, pk math (R9)
    {
      float m[4];
      v2f s[4];
#pragma unroll
      for (int r = 0; r < 4; ++r) { m[r] = -3.4e38f; s[r] = (v2f)(0.0f); }
#pragma unroll
      for (int ch = 0; ch < 2; ++ch) {
        v2f a0[4], a1[4], aq[4];
#pragma unroll
        for (int i = 0; i < 4; ++i) {
          int pi = (ch << 8) + (i << 6) + lane;  // pair index, consecutive
          a0[i] = *(const v2f*)&fy0[pi << 1];
          a1[i] = *(const v2f*)&fy1[pi << 1];
          aq[i] = *(const v2f*)&fq[pi << 1];
        }
#pragma unroll
        for (int r = 0; r < 4; ++r) {
          v2f K0 = (v2f)(fk0[r]), K1 = (v2f)(fk1[r]);
          v2f u0 = vfma(K0, a0[0], vfma(K1, a1[0], aq[0]));
          v2f u1 = vfma(K0, a0[1], vfma(K1, a1[1], aq[1]));
          v2f u2 = vfma(K0, a0[2], vfma(K1, a1[2], aq[2]));
          v2f u3 = vfma(K0, a0[3], vfma(K1, a1[3], aq[3]));
          v2f cm2 = vmax(vmax(u0, u1), vmax(u2, u3));
          float mn = fmaxf(m[r], fmaxf(cm2.x, cm2.y));
          float sc = fexp2(m[r] - mn);
          v2f mn2 = (v2f)(mn);
          v2f d0 = u0 - mn2, d1 = u1 - mn2, d2 = u2 - mn2, d3 = u3 - mn2;
          v2f e0 = {fexp2(d0.x), fexp2(d0.y)};
          v2f e1 = {fexp2(d1.x), fexp2(d1.y)};
          v2f e2 = {fexp2(d2.x), fexp2(d2.y)};
          v2f e3 = {fexp2(d3.x), fexp2(d3.y)};
          s[r] = vfma(s[r], (v2f)(sc), (e0 + e1) + (e2 + e3));
          m[r] = mn;
        }
      }
      // lane merge; lane r keeps value r; lanes 0..3 store stamped 8B
      float fout = 0.0f;
#pragma unroll
      for (int r = 0; r < 4; ++r) {
        float M = m[r];
#pragma unroll
        for (int off = 1; off <= 32; off <<= 1)
          M = fmaxf(M, __shfl_xor(M, off, 64));
        float sr = (s[r].x + s[r].y) * fexp2(m[r] - M);
#pragma unroll
        for (int off = 1; off <= 32; off <<= 1) sr += __shfl_xor(sr, off, 64);
        float v = fc0[r] - M - flog2(sr);
        if (lane == r) fout = v;
      }
      if (lane < 4) coh_store64(&F2v[frowb + lane], pack_vs(fout, sF));
    }

    // ---- stage qx = F2 - K*x2 : stamped poll reads (no barrier!)
#pragma unroll
    for (int k = 0; k < 2; ++k) {
      int e = t + (k << 10);
      gq[e] = fmaf(-K2E, xr2[k], wait_val(&F2b[e], sF));
    }
    __syncthreads();
    // ---- g-compute: online LSE over pairs, 2 cols/lane, pk math (R9)
    {
      float m[2];
      v2f s[2];
#pragma unroll
      for (int c = 0; c < 2; ++c) { m[c] = -3.4e38f; s[c] = (v2f)(0.0f); }
#pragma unroll
      for (int ch = 0; ch < 4; ++ch) {
        v2f a0[4], a1[4], aq[4];
#pragma unroll
        for (int i = 0; i < 4; ++i) {
          int pi = (ch << 8) + (i << 6) + lane;
          a0[i] = *(const v2f*)&gx0[pi << 1];
          a1[i] = *(const v2f*)&gx1[pi << 1];
          aq[i] = *(const v2f*)&gq[pi << 1];
        }
#pragma unroll
        for (int c = 0; c < 2; ++c) {
          v2f K0 = (v2f)(gk0[c]), K1 = (v2f)(gk1[c]);
          v2f u0 = vfma(K0, a0[0], vfma(K1, a1[0], aq[0]));
          v2f u1 = vfma(K0, a0[1], vfma(K1, a1[1], aq[1]));
          v2f u2 = vfma(K0, a0[2], vfma(K1, a1[2], aq[2]));
          v2f u3 = vfma(K0, a0[3], vfma(K1, a1[3], aq[3]));
          v2f cm2 = vmax(vmax(u0, u1), vmax(u2, u3));
          float mn = fmaxf(m[c], fmaxf(cm2.x, cm2.y));
          float sc = fexp2(m[c] - mn);
          v2f mn2 = (v2f)(mn);
          v2f d0 = u0 - mn2, d1 = u1 - mn2, d2 = u2 - mn2, d3 = u3 - mn2;
          v2f e0 = {fexp2(d0.x), fexp2(d0.y)};
          v2f e1 = {fexp2(d1.x), fexp2(d1.y)};
          v2f e2 = {fexp2(d2.x), fexp2(d2.y)};
          v2f e3 = {fexp2(d3.x), fexp2(d3.y)};
          s[c] = vfma(s[c], (v2f)(sc), (e0 + e1) + (e2 + e3));
          m[c] = mn;
        }
      }
      float gout = 0.0f;
#pragma unroll
      for (int c = 0; c < 2; ++c) {
        float M = m[c];
#pragma unroll
        for (int off = 1; off <= 32; off <<= 1)
          M = fmaxf(M, __shfl_xor(M, off, 64));
        float sr = (s[c].x + s[c].y) * fexp2(m[c] - M);
#pragma unroll
        for (int off = 1; off <= 32; off <<= 1) sr += __shfl_xor(sr, off, 64);
        float v = gc0[c] - M - flog2(sr);
        if (lane == c) gout = v;
      }
      if (lane < 2) coh_store64(&G2v[gcolb + lane], pack_vs(gout, sF));
    }
    // no barrier: next f's stamped staging reads enforce the dependency
  }

  // ---- fused final: poll final-stamped potentials, rowsum over own 64 rows
  if (t == 0) spart = 0.0f;
  fq[t] = fmaf(-K2E, yr2, wait_val(&G2b[t], (unsigned)ITERS));
  __syncthreads();
  float acc = 0.0f;
#pragma unroll
  for (int rr = 0; rr < 4; ++rr) {
    int row = frowb + rr;
    float2 x = preds2[row];
    float x2 = x.x * x.x + x.y * x.y;
    float qx = fmaf(-K2E, x2, wait_val(&F2v[row], (unsigned)ITERS));
#pragma unroll
    for (int i = 0; i < 16; ++i) {
      int p = (i << 6) + lane;
      float ay0 = fy0[p], ay1 = fy1[p], aqz = fq[p];
      float y2 = fmaf(ay0, ay0, ay1 * ay1);
      float tt = fmaf(x.y, ay1, x.x * ay0);
      float c = fmaxf(x2 + y2 - 2.0f * tt, 0.0f);  // clamped cost
      float v2 = fmaf(TWOK, tt, aqz + qx);         // -K*C' + F2 + G2 (base-2)
      acc = fmaf(fexp2(v2), c, acc);               // c==0 kills C'<0 case
    }
  }
#pragma unroll
  for (int off = 32; off; off >>= 1) acc += __shfl_xor(acc, off, 64);
  if (lane == 0) atomicAdd(&spart, acc);
  __syncthreads();
  if (t == 0) atomicAdd(out, spart * (1.0f / (float)BB));
}

extern "C" void kernel_launch(void* const* d_in, const int* in_sizes, int n_in,
                              void* d_out, int out_size, void* d_ws,
                              size_t ws_size, hipStream_t stream) {
  const float* preds = (const float*)d_in[0];  // [B,S,2]
  const int* labels = (const int*)d_in[1];     // [B,S]
  const float* pos = (const float*)d_in[2];    // [B,P,2]
  float* out = (float*)d_out;
  char* ws = (char*)d_ws;
  u64* G2v = (u64*)(ws);
  u64* F2v = (u64*)(ws + 65536);
  float* logb2 = (float*)(ws + 196608);

  hipLaunchKernelGGL(setup_kernel, dim3(BB), dim3(1024), 0, stream, labels,
                     G2v, logb2, out);
  hipLaunchKernelGGL(sinkhorn_persist, dim3(NBLK), dim3(NTHR), 0, stream,
                     preds, pos, logb2, F2v, G2v, out);
}